// Round 1
// baseline (237.332 us; speedup 1.0000x reference)
//
#include <hip/hip_runtime.h>
#include <hip/hip_bf16.h>
#include <cstdint>
#include <cstddef>

typedef float  f32x4  __attribute__((ext_vector_type(4)));
typedef __bf16 bf16x8 __attribute__((ext_vector_type(8)));

#define LOG2E 1.4426950408889634f

static constexpr int GN   = 8192;   // nodes
static constexpr int GIN  = 512;    // in features
static constexpr int GOUT = 256;    // out features

// ---------------- async global->LDS (width 16) ----------------
static __device__ __forceinline__ void gload_lds16(const void* g, void* lds){
  typedef uint32_t __attribute__((address_space(1)))* gp_t;
  typedef uint32_t __attribute__((address_space(3)))* lp_t;
  __builtin_amdgcn_global_load_lds((gp_t)(uintptr_t)g,
                                   (lp_t)(uint32_t)(uintptr_t)lds, 16, 0, 0);
}

// ---------------- prep kernels ----------------
// wa = (W @ a) * log2(e)   -- one wave per k (512 blocks x 64)
__global__ void k_wa(const float* __restrict__ W, const float* __restrict__ al,
                     const float* __restrict__ ar, float* __restrict__ wal,
                     float* __restrict__ war){
  int k = blockIdx.x;
  int lane = threadIdx.x;
  float4 wv = ((const float4*)(W + (size_t)k*GOUT))[lane];
  float4 av = ((const float4*)al)[lane];
  float4 bv = ((const float4*)ar)[lane];
  float sl = wv.x*av.x + wv.y*av.y + wv.z*av.z + wv.w*av.w;
  float sr = wv.x*bv.x + wv.y*bv.y + wv.z*bv.z + wv.w*bv.w;
  #pragma unroll
  for(int o=32;o;o>>=1){ sl += __shfl_down(sl,o,64); sr += __shfl_down(sr,o,64); }
  if(lane==0){ wal[k] = sl*LOG2E; war[k] = sr*LOG2E; }
}

// hb = bf16(h)
__global__ void k_h2b(const float* __restrict__ h, __bf16* __restrict__ hb){
  size_t i = ((size_t)blockIdx.x*256 + threadIdx.x)*8;
  float4 v0 = *(const float4*)(h+i);
  float4 v1 = *(const float4*)(h+i+4);
  bf16x8 o;
  o[0]=(__bf16)v0.x; o[1]=(__bf16)v0.y; o[2]=(__bf16)v0.z; o[3]=(__bf16)v0.w;
  o[4]=(__bf16)v1.x; o[5]=(__bf16)v1.y; o[6]=(__bf16)v1.z; o[7]=(__bf16)v1.w;
  *(bf16x8*)(hb+i) = o;
}

// WT[c][k] = bf16(W[k][c])
__global__ void k_wt(const float* __restrict__ W, __bf16* __restrict__ WT){
  int idx = blockIdx.x*256 + threadIdx.x;
  int k = idx >> 8, c = idx & 255;
  WT[(size_t)c*GIN + k] = (__bf16)W[idx];
}

// Wh1[i] = h[i,:] . wal ; Wh2[i] = h[i,:] . war   (fp32 exact-path scores)
__global__ void k_wh12(const float* __restrict__ h, const float* __restrict__ wal,
                       const float* __restrict__ war, float* __restrict__ Wh1,
                       float* __restrict__ Wh2){
  int row = blockIdx.x*4 + (threadIdx.x>>6);
  int lane = threadIdx.x & 63;
  const float4* hp = (const float4*)(h + (size_t)row*GIN);
  const float4* lp = (const float4*)wal;
  const float4* rp = (const float4*)war;
  float sl = 0.f, sr = 0.f;
  #pragma unroll
  for(int t=0;t<2;t++){
    float4 v = hp[lane*2+t];
    float4 a = lp[lane*2+t];
    float4 b = rp[lane*2+t];
    sl += v.x*a.x + v.y*a.y + v.z*a.z + v.w*a.w;
    sr += v.x*b.x + v.y*b.y + v.z*b.z + v.w*b.w;
  }
  #pragma unroll
  for(int o=32;o;o>>=1){ sl += __shfl_down(sl,o,64); sr += __shfl_down(sr,o,64); }
  if(lane==0){ Wh1[row]=sl; Wh2[row]=sr; }
}

// ---------------- GEMM: WhbT[m][n] = sum_k WT[m][k]*hb[n][k]  (= (h@W)^T, bf16)
// grid 256: mb=bid>>6 (4), nb=bid&63 (64); block 256 thr / 4 waves; tile 64M x 128N, KT=64
__global__ __launch_bounds__(256,1) void k_gemmT(const __bf16* __restrict__ WT,
                                                 const __bf16* __restrict__ hb,
                                                 __bf16* __restrict__ WhbT){
  __shared__ __attribute__((aligned(16))) __bf16 As[2][64*64];
  __shared__ __attribute__((aligned(16))) __bf16 Bs[2][128*64];
  const int tid = threadIdx.x, lane = tid & 63, w = tid >> 6;
  const int mb = blockIdx.x >> 6, nb = blockIdx.x & 63;
  const int m0 = mb*64, n0 = nb*128;

  f32x4 acc[8];
  #pragma unroll
  for(int t=0;t<8;t++) acc[t] = (f32x4){0.f,0.f,0.f,0.f};

  const int lr = lane>>3;                          // row-in-8-row-unit
  const int bs_sw = ((lane&7)*16) ^ (lr<<4);       // swizzled byte in 128B seg

  auto stage = [&](int it, int buf){
    const int k0b = it*128;
    #pragma unroll
    for(int s=0;s<6;s++){
      int u = w + s*4;                             // 24 units: 8 A + 16 B
      const char* src; char* dst;
      if(u < 8){
        int r8 = u*8;
        src = (const char*)(WT + (size_t)(m0 + r8 + lr)*GIN);
        dst = (char*)&As[buf][0] + r8*128;
      } else {
        int r8 = (u-8)*8;
        src = (const char*)(hb + (size_t)(n0 + r8 + lr)*GIN);
        dst = (char*)&Bs[buf][0] + r8*128;
      }
      gload_lds16(src + k0b + bs_sw, dst);
    }
  };

  auto kstep = [&](int kk, int buf){
    const int ko = kk*64 + (lane>>4)*16;
    const int am = 16*w + (lane&15);
    bf16x8 af = *(const bf16x8*)((const char*)&As[buf][0] + am*128 + (ko ^ ((am&7)<<4)));
    #pragma unroll
    for(int t=0;t<8;t++){
      int n = 16*t + (lane&15);
      bf16x8 bf = *(const bf16x8*)((const char*)&Bs[buf][0] + n*128 + (ko ^ ((n&7)<<4)));
      acc[t] = __builtin_amdgcn_mfma_f32_16x16x32_bf16(af, bf, acc[t], 0, 0, 0);
    }
  };

  stage(0,0);
  asm volatile("s_waitcnt vmcnt(0)" ::: "memory");
  __builtin_amdgcn_s_barrier();
  for(int it=0; it<8; it++){
    int buf = it & 1;
    if(it < 7) stage(it+1, buf^1);
    kstep(0, buf);
    kstep(1, buf);
    asm volatile("s_waitcnt vmcnt(0)" ::: "memory");
    __builtin_amdgcn_s_barrier();
  }

  const int mrow = m0 + 16*w + 4*(lane>>4);
  const int nc0  = n0 + (lane&15);
  #pragma unroll
  for(int t=0;t<8;t++){
    #pragma unroll
    for(int r=0;r<4;r++){
      WhbT[(size_t)(mrow + r)*GN + nc0 + 16*t] = (__bf16)acc[t][r];
    }
  }
}

// ---------------- fused masked-softmax-attention (no-max flash, atomic 2-way combine)
// grid 256: rg=bid>>1 (row group of 64), half=bid&1 (4096 cols); 256 thr / 4 waves
__global__ __launch_bounds__(256,1) void k_attn(const int* __restrict__ adj,
                                                const __bf16* __restrict__ WhbT,
                                                const float* __restrict__ Wh1s,
                                                const float* __restrict__ Wh2s,
                                                float* __restrict__ accPV,
                                                float* __restrict__ accS){
  __shared__ __attribute__((aligned(16))) __bf16 Vs[2][256*64];
  const int tid = threadIdx.x, lane = tid & 63, w = tid >> 6;
  const int rg = blockIdx.x >> 1, half = blockIdx.x & 1;
  const int r0 = rg * 64;
  const int j0 = half * 4096;

  f32x4 acc[16];
  #pragma unroll
  for(int t=0;t<16;t++) acc[t] = (f32x4){0.f,0.f,0.f,0.f};
  f32x4 accs = (f32x4){0.f,0.f,0.f,0.f};

  bf16x8 ones;
  #pragma unroll
  for(int j=0;j<8;j++) ones[j] = (__bf16)1.0f;

  const int kg = lane >> 4;
  const int myrow = r0 + 16*w + (lane & 15);
  const float wh1 = Wh1s[myrow];                    // pre-scaled by log2(e)
  const int*   adjrow = adj  + (size_t)myrow*GN + j0 + kg*8;
  const float* wh2p   = Wh2s + j0 + kg*8;

  const int lr = lane>>3;
  const int bs_sw = ((lane&7)*16) ^ (lr<<4);

  auto stage = [&](int it, int buf){
    const int colb = (j0 + it*64)*2;
    #pragma unroll
    for(int s=0;s<8;s++){
      int u = w + s*4;                              // 32 units of 8 rows
      int r8 = u*8;
      const char* src = (const char*)WhbT + (size_t)(r8 + lr)*(GN*2) + colb + bs_sw;
      gload_lds16(src, (char*)&Vs[buf][0] + r8*128);
    }
  };

  auto kstep = [&](int it, int kk, int buf){
    const int* ap = adjrow + it*64 + kk*32;
    int4 a0 = *(const int4*)ap;
    int4 a1 = *(const int4*)(ap + 4);
    const float* wp = wh2p + it*64 + kk*32;
    float4 w0 = *(const float4*)wp;
    float4 w1 = *(const float4*)(wp + 4);
    bf16x8 pa;
    {
      float y, p;
      y = wh1 + w0.x; y = fmaxf(y, 0.2f*y); p = exp2f(y); pa[0] = (__bf16)(a0.x ? p : 0.f);
      y = wh1 + w0.y; y = fmaxf(y, 0.2f*y); p = exp2f(y); pa[1] = (__bf16)(a0.y ? p : 0.f);
      y = wh1 + w0.z; y = fmaxf(y, 0.2f*y); p = exp2f(y); pa[2] = (__bf16)(a0.z ? p : 0.f);
      y = wh1 + w0.w; y = fmaxf(y, 0.2f*y); p = exp2f(y); pa[3] = (__bf16)(a0.w ? p : 0.f);
      y = wh1 + w1.x; y = fmaxf(y, 0.2f*y); p = exp2f(y); pa[4] = (__bf16)(a1.x ? p : 0.f);
      y = wh1 + w1.y; y = fmaxf(y, 0.2f*y); p = exp2f(y); pa[5] = (__bf16)(a1.y ? p : 0.f);
      y = wh1 + w1.z; y = fmaxf(y, 0.2f*y); p = exp2f(y); pa[6] = (__bf16)(a1.z ? p : 0.f);
      y = wh1 + w1.w; y = fmaxf(y, 0.2f*y); p = exp2f(y); pa[7] = (__bf16)(a1.w ? p : 0.f);
    }
    const int ko = kk*64 + kg*16;
    #pragma unroll
    for(int t=0;t<16;t++){
      int n = 16*t + (lane&15);
      bf16x8 bv = *(const bf16x8*)((const char*)&Vs[buf][0] + n*128 + (ko ^ ((n&7)<<4)));
      acc[t] = __builtin_amdgcn_mfma_f32_16x16x32_bf16(pa, bv, acc[t], 0, 0, 0);
    }
    accs = __builtin_amdgcn_mfma_f32_16x16x32_bf16(pa, ones, accs, 0, 0, 0);
  };

  stage(0, 0);
  asm volatile("s_waitcnt vmcnt(0)" ::: "memory");
  __builtin_amdgcn_s_barrier();
  for(int it=0; it<64; it++){
    int buf = it & 1;
    if(it < 63) stage(it+1, buf^1);
    kstep(it, 0, buf);
    kstep(it, 1, buf);
    asm volatile("s_waitcnt vmcnt(0)" ::: "memory");
    __builtin_amdgcn_s_barrier();
  }

  const int orow = r0 + 16*w + 4*kg;
  const int ocol = lane & 15;
  #pragma unroll
  for(int t=0;t<16;t++){
    #pragma unroll
    for(int r=0;r<4;r++){
      atomicAdd(accPV + (size_t)(orow + r)*GOUT + ocol + 16*t, acc[t][r]);
    }
  }
  if(ocol == 0){
    #pragma unroll
    for(int r=0;r<4;r++) atomicAdd(accS + orow + r, accs[r]);
  }
}

// ---------------- normalize + ELU ----------------
static __device__ __forceinline__ float elu1(float x){
  return x > 0.f ? x : (exp2f(x*LOG2E) - 1.f);
}
__global__ void k_norm(const float* __restrict__ accPV, const float* __restrict__ accS,
                       float* __restrict__ out){
  size_t i = ((size_t)blockIdx.x*256 + threadIdx.x)*4;
  int row = (int)(i >> 8);
  float inv = 1.0f / accS[row];
  float4 v = *(const float4*)(accPV + i);
  float4 o;
  o.x = elu1(v.x*inv); o.y = elu1(v.y*inv); o.z = elu1(v.z*inv); o.w = elu1(v.w*inv);
  *(float4*)(out + i) = o;
}

// ---------------- launch ----------------
extern "C" void kernel_launch(void* const* d_in, const int* in_sizes, int n_in,
                              void* d_out, int out_size, void* d_ws, size_t ws_size,
                              hipStream_t stream){
  const float* h  = (const float*)d_in[0];
  const int*   adj= (const int*)  d_in[1];
  const float* W  = (const float*)d_in[2];
  const float* al = (const float*)d_in[3];
  const float* ar = (const float*)d_in[4];
  float* out = (float*)d_out;

  char* ws = (char*)d_ws;
  // layout (bytes)
  float*  accPV = (float*) (ws);                       //  8,388,608
  float*  accS  = (float*) (ws + 8388608);             //     32,768
  __bf16* hb    = (__bf16*)(ws + 8421376);             //  8,388,608
  __bf16* WT    = (__bf16*)(ws + 16809984);            //    262,144
  __bf16* WhbT  = (__bf16*)(ws + 17072128);            //  4,194,304
  float*  wal   = (float*) (ws + 21266432);            //      2,048
  float*  war   = (float*) (ws + 21268480);            //      2,048
  float*  Wh1   = (float*) (ws + 21270528);            //     32,768
  float*  Wh2   = (float*) (ws + 21303296);            //     32,768
  if(ws_size < 21336064) return;                       // need ~20.4 MiB

  hipMemsetAsync(accPV, 0, 8388608 + 32768, stream);   // zero PV+S accumulators

  k_wa  <<<512, 64, 0, stream>>>(W, al, ar, wal, war);
  k_h2b <<<2048, 256, 0, stream>>>(h, hb);
  k_wt  <<<512, 256, 0, stream>>>(W, WT);
  k_wh12<<<2048, 256, 0, stream>>>(h, wal, war, Wh1, Wh2);
  k_gemmT<<<256, 256, 0, stream>>>(WT, hb, WhbT);
  k_attn<<<256, 256, 0, stream>>>(adj, WhbT, Wh1, Wh2, accPV, accS);
  k_norm<<<2048, 256, 0, stream>>>(accPV, accS, out);
}

// Round 2
// 154.464 us; speedup vs baseline: 1.5365x; 1.5365x over previous
//
#include <hip/hip_runtime.h>
#include <hip/hip_bf16.h>
#include <cstdint>
#include <cstddef>

typedef float  f32x4  __attribute__((ext_vector_type(4)));
typedef __bf16 bf16x8 __attribute__((ext_vector_type(8)));

#define LOG2E 1.4426950408889634f

static constexpr int GN   = 8192;   // nodes
static constexpr int GIN  = 512;    // in features
static constexpr int GOUT = 256;    // out features

// ---------------- async global->LDS (width 16) ----------------
static __device__ __forceinline__ void gload_lds16(const void* g, void* lds){
  typedef uint32_t __attribute__((address_space(1)))* gp_t;
  typedef uint32_t __attribute__((address_space(3)))* lp_t;
  __builtin_amdgcn_global_load_lds((gp_t)(uintptr_t)g,
                                   (lp_t)(uint32_t)(uintptr_t)lds, 16, 0, 0);
}

// ---------------- prep kernels ----------------
// wa = (W @ a) * log2(e)   -- one wave per k (512 blocks x 64)
__global__ void k_wa(const float* __restrict__ W, const float* __restrict__ al,
                     const float* __restrict__ ar, float* __restrict__ wal,
                     float* __restrict__ war){
  int k = blockIdx.x;
  int lane = threadIdx.x;
  float4 wv = ((const float4*)(W + (size_t)k*GOUT))[lane];
  float4 av = ((const float4*)al)[lane];
  float4 bv = ((const float4*)ar)[lane];
  float sl = wv.x*av.x + wv.y*av.y + wv.z*av.z + wv.w*av.w;
  float sr = wv.x*bv.x + wv.y*bv.y + wv.z*bv.z + wv.w*bv.w;
  #pragma unroll
  for(int o=32;o;o>>=1){ sl += __shfl_down(sl,o,64); sr += __shfl_down(sr,o,64); }
  if(lane==0){ wal[k] = sl*LOG2E; war[k] = sr*LOG2E; }
}

// hb = bf16(h)
__global__ void k_h2b(const float* __restrict__ h, __bf16* __restrict__ hb){
  size_t i = ((size_t)blockIdx.x*256 + threadIdx.x)*8;
  float4 v0 = *(const float4*)(h+i);
  float4 v1 = *(const float4*)(h+i+4);
  bf16x8 o;
  o[0]=(__bf16)v0.x; o[1]=(__bf16)v0.y; o[2]=(__bf16)v0.z; o[3]=(__bf16)v0.w;
  o[4]=(__bf16)v1.x; o[5]=(__bf16)v1.y; o[6]=(__bf16)v1.z; o[7]=(__bf16)v1.w;
  *(bf16x8*)(hb+i) = o;
}

// WT[c][k] = bf16(W[k][c])
__global__ void k_wt(const float* __restrict__ W, __bf16* __restrict__ WT){
  int idx = blockIdx.x*256 + threadIdx.x;
  int k = idx >> 8, c = idx & 255;
  WT[(size_t)c*GIN + k] = (__bf16)W[idx];
}

// Wh1[i] = h[i,:] . wal ; Wh2[i] = h[i,:] . war   (fp32 exact-path scores)
__global__ void k_wh12(const float* __restrict__ h, const float* __restrict__ wal,
                       const float* __restrict__ war, float* __restrict__ Wh1,
                       float* __restrict__ Wh2){
  int row = blockIdx.x*4 + (threadIdx.x>>6);
  int lane = threadIdx.x & 63;
  const float4* hp = (const float4*)(h + (size_t)row*GIN);
  const float4* lp = (const float4*)wal;
  const float4* rp = (const float4*)war;
  float sl = 0.f, sr = 0.f;
  #pragma unroll
  for(int t=0;t<2;t++){
    float4 v = hp[lane*2+t];
    float4 a = lp[lane*2+t];
    float4 b = rp[lane*2+t];
    sl += v.x*a.x + v.y*a.y + v.z*a.z + v.w*a.w;
    sr += v.x*b.x + v.y*b.y + v.z*b.z + v.w*b.w;
  }
  #pragma unroll
  for(int o=32;o;o>>=1){ sl += __shfl_down(sl,o,64); sr += __shfl_down(sr,o,64); }
  if(lane==0){ Wh1[row]=sl; Wh2[row]=sr; }
}

// ---------------- GEMM: WhbT[m][n] = sum_k WT[m][k]*hb[n][k]  (= (h@W)^T, bf16)
__global__ __launch_bounds__(256,1) void k_gemmT(const __bf16* __restrict__ WT,
                                                 const __bf16* __restrict__ hb,
                                                 __bf16* __restrict__ WhbT){
  __shared__ __attribute__((aligned(16))) __bf16 As[2][64*64];
  __shared__ __attribute__((aligned(16))) __bf16 Bs[2][128*64];
  const int tid = threadIdx.x, lane = tid & 63, w = tid >> 6;
  const int mb = blockIdx.x >> 6, nb = blockIdx.x & 63;
  const int m0 = mb*64, n0 = nb*128;

  f32x4 acc[8];
  #pragma unroll
  for(int t=0;t<8;t++) acc[t] = (f32x4){0.f,0.f,0.f,0.f};

  const int lr = lane>>3;                          // row-in-8-row-unit
  const int bs_sw = ((lane&7)*16) ^ (lr<<4);       // swizzled byte in 128B seg

  auto stage = [&](int it, int buf){
    const int k0b = it*128;
    #pragma unroll
    for(int s=0;s<6;s++){
      int u = w + s*4;                             // 24 units: 8 A + 16 B
      const char* src; char* dst;
      if(u < 8){
        int r8 = u*8;
        src = (const char*)(WT + (size_t)(m0 + r8 + lr)*GIN);
        dst = (char*)&As[buf][0] + r8*128;
      } else {
        int r8 = (u-8)*8;
        src = (const char*)(hb + (size_t)(n0 + r8 + lr)*GIN);
        dst = (char*)&Bs[buf][0] + r8*128;
      }
      gload_lds16(src + k0b + bs_sw, dst);
    }
  };

  auto kstep = [&](int kk, int buf){
    const int ko = kk*64 + (lane>>4)*16;
    const int am = 16*w + (lane&15);
    bf16x8 af = *(const bf16x8*)((const char*)&As[buf][0] + am*128 + (ko ^ ((am&7)<<4)));
    #pragma unroll
    for(int t=0;t<8;t++){
      int n = 16*t + (lane&15);
      bf16x8 bf = *(const bf16x8*)((const char*)&Bs[buf][0] + n*128 + (ko ^ ((n&7)<<4)));
      acc[t] = __builtin_amdgcn_mfma_f32_16x16x32_bf16(af, bf, acc[t], 0, 0, 0);
    }
  };

  stage(0,0);
  asm volatile("s_waitcnt vmcnt(0)" ::: "memory");
  __builtin_amdgcn_s_barrier();
  for(int it=0; it<8; it++){
    int buf = it & 1;
    if(it < 7) stage(it+1, buf^1);
    kstep(0, buf);
    kstep(1, buf);
    asm volatile("s_waitcnt vmcnt(0)" ::: "memory");
    __builtin_amdgcn_s_barrier();
  }

  const int mrow = m0 + 16*w + 4*(lane>>4);
  const int nc0  = n0 + (lane&15);
  #pragma unroll
  for(int t=0;t<8;t++){
    #pragma unroll
    for(int r=0;r<4;r++){
      WhbT[(size_t)(mrow + r)*GN + nc0 + 16*t] = (__bf16)acc[t][r];
    }
  }
}

// ---------------- fused masked-softmax-attention (no-max flash, atomic 8-way combine)
// grid 512: rg=bid>>3 (64 rowgroups of 128), chunk=bid&7 (1024 cols)
// block 256 thr / 4 waves; each wave owns TWO 16-row subtiles (rows +0 and +64)
// sharing every B-fragment load -> halves LDS read volume per row.
__global__ __launch_bounds__(256,2) void k_attn(const int* __restrict__ adj,
                                                const __bf16* __restrict__ WhbT,
                                                const float* __restrict__ Wh1s,
                                                const float* __restrict__ Wh2s,
                                                float* __restrict__ accPV,
                                                float* __restrict__ accS){
  __shared__ __attribute__((aligned(16))) __bf16 Vs[2][256*64];
  const int tid = threadIdx.x, lane = tid & 63, w = tid >> 6;
  const int rg = blockIdx.x >> 3, chunk = blockIdx.x & 7;
  const int r0 = rg * 128;
  const int j0 = chunk * 1024;

  f32x4 acc0[16], acc1[16];
  #pragma unroll
  for(int t=0;t<16;t++){ acc0[t] = (f32x4){0.f,0.f,0.f,0.f}; acc1[t] = (f32x4){0.f,0.f,0.f,0.f}; }
  f32x4 accs0 = (f32x4){0.f,0.f,0.f,0.f};
  f32x4 accs1 = (f32x4){0.f,0.f,0.f,0.f};

  bf16x8 ones;
  #pragma unroll
  for(int j=0;j<8;j++) ones[j] = (__bf16)1.0f;

  const int kg = lane >> 4;
  const int myrow0 = r0 + 16*w + (lane & 15);
  const int myrow1 = myrow0 + 64;
  const float wh1_0 = Wh1s[myrow0];                 // pre-scaled by log2(e)
  const float wh1_1 = Wh1s[myrow1];
  const int*   adjrow0 = adj  + (size_t)myrow0*GN + j0 + kg*8;
  const int*   adjrow1 = adj  + (size_t)myrow1*GN + j0 + kg*8;
  const float* wh2p    = Wh2s + j0 + kg*8;

  const int lr = lane>>3;
  const int bs_sw = ((lane&7)*16) ^ (lr<<4);

  auto stage = [&](int it, int buf){
    const int colb = (j0 + it*64)*2;
    #pragma unroll
    for(int s=0;s<8;s++){
      int u = w + s*4;                              // 32 units of 8 rows
      int r8 = u*8;
      const char* src = (const char*)WhbT + (size_t)(r8 + lr)*(GN*2) + colb + bs_sw;
      gload_lds16(src, (char*)&Vs[buf][0] + r8*128);
    }
  };

  auto mkpa = [&](float wh1, int4 a0, int4 a1, float4 w0, float4 w1) -> bf16x8 {
    bf16x8 pa;
    float y, p;
    y = wh1 + w0.x; y = fmaxf(y, 0.2f*y); p = exp2f(y); pa[0] = (__bf16)(a0.x ? p : 0.f);
    y = wh1 + w0.y; y = fmaxf(y, 0.2f*y); p = exp2f(y); pa[1] = (__bf16)(a0.y ? p : 0.f);
    y = wh1 + w0.z; y = fmaxf(y, 0.2f*y); p = exp2f(y); pa[2] = (__bf16)(a0.z ? p : 0.f);
    y = wh1 + w0.w; y = fmaxf(y, 0.2f*y); p = exp2f(y); pa[3] = (__bf16)(a0.w ? p : 0.f);
    y = wh1 + w1.x; y = fmaxf(y, 0.2f*y); p = exp2f(y); pa[4] = (__bf16)(a1.x ? p : 0.f);
    y = wh1 + w1.y; y = fmaxf(y, 0.2f*y); p = exp2f(y); pa[5] = (__bf16)(a1.y ? p : 0.f);
    y = wh1 + w1.z; y = fmaxf(y, 0.2f*y); p = exp2f(y); pa[6] = (__bf16)(a1.z ? p : 0.f);
    y = wh1 + w1.w; y = fmaxf(y, 0.2f*y); p = exp2f(y); pa[7] = (__bf16)(a1.w ? p : 0.f);
    return pa;
  };

  auto kstep = [&](int it, int kk, int buf){
    const int off = it*64 + kk*32;
    const int* ap0 = adjrow0 + off;
    const int* ap1 = adjrow1 + off;
    int4 a00 = *(const int4*)ap0;  int4 a01 = *(const int4*)(ap0 + 4);
    int4 a10 = *(const int4*)ap1;  int4 a11 = *(const int4*)(ap1 + 4);
    const float* wp = wh2p + off;
    float4 w0 = *(const float4*)wp;
    float4 w1 = *(const float4*)(wp + 4);
    bf16x8 pa0 = mkpa(wh1_0, a00, a01, w0, w1);
    bf16x8 pa1 = mkpa(wh1_1, a10, a11, w0, w1);
    const int ko = kk*64 + kg*16;
    #pragma unroll
    for(int t=0;t<16;t++){
      int n = 16*t + (lane&15);
      bf16x8 bv = *(const bf16x8*)((const char*)&Vs[buf][0] + n*128 + (ko ^ ((n&7)<<4)));
      acc0[t] = __builtin_amdgcn_mfma_f32_16x16x32_bf16(pa0, bv, acc0[t], 0, 0, 0);
      acc1[t] = __builtin_amdgcn_mfma_f32_16x16x32_bf16(pa1, bv, acc1[t], 0, 0, 0);
    }
    accs0 = __builtin_amdgcn_mfma_f32_16x16x32_bf16(pa0, ones, accs0, 0, 0, 0);
    accs1 = __builtin_amdgcn_mfma_f32_16x16x32_bf16(pa1, ones, accs1, 0, 0, 0);
  };

  stage(0, 0);
  asm volatile("s_waitcnt vmcnt(0)" ::: "memory");
  __builtin_amdgcn_s_barrier();
  for(int it=0; it<16; it++){
    int buf = it & 1;
    if(it < 15) stage(it+1, buf^1);
    kstep(it, 0, buf);
    kstep(it, 1, buf);
    asm volatile("s_waitcnt vmcnt(0)" ::: "memory");
    __builtin_amdgcn_s_barrier();
  }

  const int orow0 = r0 + 16*w + 4*kg;
  const int orow1 = orow0 + 64;
  const int ocol  = lane & 15;
  #pragma unroll
  for(int t=0;t<16;t++){
    #pragma unroll
    for(int r=0;r<4;r++){
      atomicAdd(accPV + (size_t)(orow0 + r)*GOUT + ocol + 16*t, acc0[t][r]);
      atomicAdd(accPV + (size_t)(orow1 + r)*GOUT + ocol + 16*t, acc1[t][r]);
    }
  }
  if(ocol == 0){
    #pragma unroll
    for(int r=0;r<4;r++){
      atomicAdd(accS + orow0 + r, accs0[r]);
      atomicAdd(accS + orow1 + r, accs1[r]);
    }
  }
}

// ---------------- normalize + ELU ----------------
static __device__ __forceinline__ float elu1(float x){
  return x > 0.f ? x : (exp2f(x*LOG2E) - 1.f);
}
__global__ void k_norm(const float* __restrict__ accPV, const float* __restrict__ accS,
                       float* __restrict__ out){
  size_t i = ((size_t)blockIdx.x*256 + threadIdx.x)*4;
  int row = (int)(i >> 8);
  float inv = 1.0f / accS[row];
  float4 v = *(const float4*)(accPV + i);
  float4 o;
  o.x = elu1(v.x*inv); o.y = elu1(v.y*inv); o.z = elu1(v.z*inv); o.w = elu1(v.w*inv);
  *(float4*)(out + i) = o;
}

// ---------------- launch ----------------
extern "C" void kernel_launch(void* const* d_in, const int* in_sizes, int n_in,
                              void* d_out, int out_size, void* d_ws, size_t ws_size,
                              hipStream_t stream){
  const float* h  = (const float*)d_in[0];
  const int*   adj= (const int*)  d_in[1];
  const float* W  = (const float*)d_in[2];
  const float* al = (const float*)d_in[3];
  const float* ar = (const float*)d_in[4];
  float* out = (float*)d_out;

  char* ws = (char*)d_ws;
  // layout (bytes)
  float*  accPV = (float*) (ws);                       //  8,388,608
  float*  accS  = (float*) (ws + 8388608);             //     32,768
  __bf16* hb    = (__bf16*)(ws + 8421376);             //  8,388,608
  __bf16* WT    = (__bf16*)(ws + 16809984);            //    262,144
  __bf16* WhbT  = (__bf16*)(ws + 17072128);            //  4,194,304
  float*  wal   = (float*) (ws + 21266432);            //      2,048
  float*  war   = (float*) (ws + 21268480);            //      2,048
  float*  Wh1   = (float*) (ws + 21270528);            //     32,768
  float*  Wh2   = (float*) (ws + 21303296);            //     32,768
  if(ws_size < 21336064) return;                       // need ~20.4 MiB

  hipMemsetAsync(accPV, 0, 8388608 + 32768, stream);   // zero PV+S accumulators

  k_wa  <<<512, 64, 0, stream>>>(W, al, ar, wal, war);
  k_h2b <<<2048, 256, 0, stream>>>(h, hb);
  k_wt  <<<512, 256, 0, stream>>>(W, WT);
  k_wh12<<<2048, 256, 0, stream>>>(h, wal, war, Wh1, Wh2);
  k_gemmT<<<256, 256, 0, stream>>>(WT, hb, WhbT);
  k_attn<<<512, 256, 0, stream>>>(adj, WhbT, Wh1, Wh2, accPV, accS);
  k_norm<<<2048, 256, 0, stream>>>(accPV, accS, out);
}

// Round 4
// 138.621 us; speedup vs baseline: 1.7121x; 1.1143x over previous
//
#include <hip/hip_runtime.h>
#include <hip/hip_bf16.h>
#include <cstdint>
#include <cstddef>

typedef float  f32x4  __attribute__((ext_vector_type(4)));
typedef __bf16 bf16x8 __attribute__((ext_vector_type(8)));

#define LOG2E 1.4426950408889634f

static constexpr int GN   = 8192;   // nodes
static constexpr int GIN  = 512;    // in features
static constexpr int GOUT = 256;    // out features

// ---------------- async global->LDS (width 16) ----------------
static __device__ __forceinline__ void gload_lds16(const void* g, void* lds){
  typedef uint32_t __attribute__((address_space(1)))* gp_t;
  typedef uint32_t __attribute__((address_space(3)))* lp_t;
  __builtin_amdgcn_global_load_lds((gp_t)(uintptr_t)g,
                                   (lp_t)(uint32_t)(uintptr_t)lds, 16, 0, 0);
}

// ---------------- prep kernels ----------------
// wa = (W @ a) * log2(e)   -- one wave per k (512 blocks x 64)
__global__ void k_wa(const float* __restrict__ W, const float* __restrict__ al,
                     const float* __restrict__ ar, float* __restrict__ wal,
                     float* __restrict__ war){
  int k = blockIdx.x;
  int lane = threadIdx.x;
  float4 wv = ((const float4*)(W + (size_t)k*GOUT))[lane];
  float4 av = ((const float4*)al)[lane];
  float4 bv = ((const float4*)ar)[lane];
  float sl = wv.x*av.x + wv.y*av.y + wv.z*av.z + wv.w*av.w;
  float sr = wv.x*bv.x + wv.y*bv.y + wv.z*bv.z + wv.w*bv.w;
  #pragma unroll
  for(int o=32;o;o>>=1){ sl += __shfl_down(sl,o,64); sr += __shfl_down(sr,o,64); }
  if(lane==0){ wal[k] = sl*LOG2E; war[k] = sr*LOG2E; }
}

// fused: hb = bf16(h); Wh1/Wh2 fp32 row-dots. 4 rows/block.
__global__ void k_prep_h(const float* __restrict__ h, const float* __restrict__ wal,
                         const float* __restrict__ war, __bf16* __restrict__ hb,
                         float* __restrict__ Wh1, float* __restrict__ Wh2){
  int row = blockIdx.x*4 + (threadIdx.x>>6);
  int lane = threadIdx.x & 63;
  const float4* hp = (const float4*)(h + (size_t)row*GIN);
  float4 v0 = hp[lane*2], v1 = hp[lane*2+1];
  bf16x8 o;
  o[0]=(__bf16)v0.x; o[1]=(__bf16)v0.y; o[2]=(__bf16)v0.z; o[3]=(__bf16)v0.w;
  o[4]=(__bf16)v1.x; o[5]=(__bf16)v1.y; o[6]=(__bf16)v1.z; o[7]=(__bf16)v1.w;
  *(bf16x8*)(hb + (size_t)row*GIN + lane*8) = o;
  float4 a0 = ((const float4*)wal)[lane*2], a1 = ((const float4*)wal)[lane*2+1];
  float4 b0 = ((const float4*)war)[lane*2], b1 = ((const float4*)war)[lane*2+1];
  float sl = v0.x*a0.x+v0.y*a0.y+v0.z*a0.z+v0.w*a0.w
           + v1.x*a1.x+v1.y*a1.y+v1.z*a1.z+v1.w*a1.w;
  float sr = v0.x*b0.x+v0.y*b0.y+v0.z*b0.z+v0.w*b0.w
           + v1.x*b1.x+v1.y*b1.y+v1.z*b1.z+v1.w*b1.w;
  #pragma unroll
  for(int of=32;of;of>>=1){ sl += __shfl_down(sl,of,64); sr += __shfl_down(sr,of,64); }
  if(lane==0){ Wh1[row]=sl; Wh2[row]=sr; }
}

// WT[c][k] = bf16(W[k][c])
__global__ void k_wt(const float* __restrict__ W, __bf16* __restrict__ WT){
  int idx = blockIdx.x*256 + threadIdx.x;
  int k = idx >> 8, c = idx & 255;
  WT[(size_t)c*GIN + k] = (__bf16)W[idx];
}

// ---------------- GEMM: WhbT[m][n] = sum_k WT[m][k]*hb[n][k]  (= (h@W)^T, bf16)
__global__ __launch_bounds__(256,1) void k_gemmT(const __bf16* __restrict__ WT,
                                                 const __bf16* __restrict__ hb,
                                                 __bf16* __restrict__ WhbT){
  __shared__ __attribute__((aligned(16))) __bf16 As[2][64*64];
  __shared__ __attribute__((aligned(16))) __bf16 Bs[2][128*64];
  const int tid = threadIdx.x, lane = tid & 63, w = tid >> 6;
  const int mb = blockIdx.x >> 6, nb = blockIdx.x & 63;
  const int m0 = mb*64, n0 = nb*128;

  f32x4 acc[8];
  #pragma unroll
  for(int t=0;t<8;t++) acc[t] = (f32x4){0.f,0.f,0.f,0.f};

  const int lr = lane>>3;
  const int bs_sw = ((lane&7)*16) ^ (lr<<4);

  auto stage = [&](int it, int buf){
    const int k0b = it*128;
    #pragma unroll
    for(int s=0;s<6;s++){
      int u = w + s*4;
      const char* src; char* dst;
      if(u < 8){
        int r8 = u*8;
        src = (const char*)(WT + (size_t)(m0 + r8 + lr)*GIN);
        dst = (char*)&As[buf][0] + r8*128;
      } else {
        int r8 = (u-8)*8;
        src = (const char*)(hb + (size_t)(n0 + r8 + lr)*GIN);
        dst = (char*)&Bs[buf][0] + r8*128;
      }
      gload_lds16(src + k0b + bs_sw, dst);
    }
  };

  auto kstep = [&](int kk, int buf){
    const int ko = kk*64 + (lane>>4)*16;
    const int am = 16*w + (lane&15);
    bf16x8 af = *(const bf16x8*)((const char*)&As[buf][0] + am*128 + (ko ^ ((am&7)<<4)));
    #pragma unroll
    for(int t=0;t<8;t++){
      int n = 16*t + (lane&15);
      bf16x8 bf = *(const bf16x8*)((const char*)&Bs[buf][0] + n*128 + (ko ^ ((n&7)<<4)));
      acc[t] = __builtin_amdgcn_mfma_f32_16x16x32_bf16(af, bf, acc[t], 0, 0, 0);
    }
  };

  stage(0,0);
  asm volatile("s_waitcnt vmcnt(0)" ::: "memory");
  __builtin_amdgcn_s_barrier();
  for(int it=0; it<8; it++){
    int buf = it & 1;
    if(it < 7) stage(it+1, buf^1);
    kstep(0, buf);
    kstep(1, buf);
    asm volatile("s_waitcnt vmcnt(0)" ::: "memory");
    __builtin_amdgcn_s_barrier();
  }

  const int mrow = m0 + 16*w + 4*(lane>>4);
  const int nc0  = n0 + (lane&15);
  #pragma unroll
  for(int t=0;t<8;t++){
    #pragma unroll
    for(int r=0;r<4;r++){
      WhbT[(size_t)(mrow + r)*GN + nc0 + 16*t] = (__bf16)acc[t][r];
    }
  }
}

// ---------------- fused masked-softmax-attention ----------------
// grid 512: rg=bid>>3 (64 rowgroups of 128), chunk=bid&7 (1024 cols)
// adj is read COALESCED (adj[row][j+lane]) and ballot-packed to per-lane u64 masks.
// PART=true: write fp32 partials (no atomics); PART=false: atomicAdd combine.
template<bool PART>
__global__ __launch_bounds__(256,2) void k_attn(const int* __restrict__ adj,
                                                const __bf16* __restrict__ WhbT,
                                                const float* __restrict__ Wh1s,
                                                const float* __restrict__ Wh2s,
                                                float* __restrict__ pv_out,
                                                float* __restrict__ s_out){
  __shared__ __attribute__((aligned(16))) __bf16 Vs[2][256*64];
  const int tid = threadIdx.x, lane = tid & 63, w = tid >> 6;
  const int rg = blockIdx.x >> 3, chunk = blockIdx.x & 7;
  const int r0 = rg * 128;
  const int j0 = chunk * 1024;

  f32x4 acc0[16], acc1[16];
  #pragma unroll
  for(int t=0;t<16;t++){ acc0[t] = (f32x4){0.f,0.f,0.f,0.f}; acc1[t] = (f32x4){0.f,0.f,0.f,0.f}; }
  f32x4 accs0 = (f32x4){0.f,0.f,0.f,0.f};
  f32x4 accs1 = (f32x4){0.f,0.f,0.f,0.f};

  bf16x8 ones;
  #pragma unroll
  for(int j=0;j<8;j++) ones[j] = (__bf16)1.0f;

  const int kg  = lane >> 4;
  const int kg8 = kg << 3;
  const int myrow0 = r0 + 16*w + (lane & 15);
  const float wh1_0 = Wh1s[myrow0];                 // pre-scaled by log2(e)
  const float wh1_1 = Wh1s[myrow0 + 64];
  const float* wh2p = Wh2s + j0 + kg8;

  // adj base rows this wave packs: set0 = r0+16w+r, set1 = +64 (r=0..15)
  const size_t arow0 = (size_t)(r0 + 16*w) * GN + j0;
  const size_t arow1 = arow0 + (size_t)64 * GN;

  const int lr = lane>>3;
  const int bs_sw = ((lane&7)*16) ^ (lr<<4);

  auto stage = [&](int it, int buf){
    const int colb = (j0 + it*64)*2;
    #pragma unroll
    for(int s=0;s<8;s++){
      int u = w + s*4;
      int r8 = u*8;
      const char* src = (const char*)WhbT + (size_t)(r8 + lr)*(GN*2) + colb + bs_sw;
      gload_lds16(src, (char*)&Vs[buf][0] + r8*128);
    }
  };

  int a0p[16], a1p[16];
  auto adj_load = [&](int tt){
    const int co = tt*64 + lane;
    #pragma unroll
    for(int r=0;r<16;r++) a0p[r] = adj[arow0 + (size_t)r*GN + co];
    #pragma unroll
    for(int r=0;r<16;r++) a1p[r] = adj[arow1 + (size_t)r*GN + co];
  };
  auto adj_pack = [&](uint64_t& m0, uint64_t& m1){
    uint64_t n0 = 0, n1 = 0;
    #pragma unroll
    for(int r=0;r<16;r++){
      uint64_t b = __ballot(a0p[r] != 0);
      if((lane&15)==r) n0 = b;
    }
    #pragma unroll
    for(int r=0;r<16;r++){
      uint64_t b = __ballot(a1p[r] != 0);
      if((lane&15)==r) n1 = b;
    }
    m0 = n0; m1 = n1;
  };

  auto mkpa = [&](float wh1, unsigned m8, float4 w0, float4 w1) -> bf16x8 {
    bf16x8 pa;
    float y, p;
    y = wh1 + w0.x; y = fmaxf(y, 0.2f*y); p = exp2f(y); pa[0] = (__bf16)((m8    )&1 ? p : 0.f);
    y = wh1 + w0.y; y = fmaxf(y, 0.2f*y); p = exp2f(y); pa[1] = (__bf16)((m8>>1)&1 ? p : 0.f);
    y = wh1 + w0.z; y = fmaxf(y, 0.2f*y); p = exp2f(y); pa[2] = (__bf16)((m8>>2)&1 ? p : 0.f);
    y = wh1 + w0.w; y = fmaxf(y, 0.2f*y); p = exp2f(y); pa[3] = (__bf16)((m8>>3)&1 ? p : 0.f);
    y = wh1 + w1.x; y = fmaxf(y, 0.2f*y); p = exp2f(y); pa[4] = (__bf16)((m8>>4)&1 ? p : 0.f);
    y = wh1 + w1.y; y = fmaxf(y, 0.2f*y); p = exp2f(y); pa[5] = (__bf16)((m8>>5)&1 ? p : 0.f);
    y = wh1 + w1.z; y = fmaxf(y, 0.2f*y); p = exp2f(y); pa[6] = (__bf16)((m8>>6)&1 ? p : 0.f);
    y = wh1 + w1.w; y = fmaxf(y, 0.2f*y); p = exp2f(y); pa[7] = (__bf16)((m8>>7)&1 ? p : 0.f);
    return pa;
  };

  uint64_t mk0, mk1;

  auto kstep = [&](int it, int kk, int buf){
    const float* wp = wh2p + it*64 + kk*32;
    float4 w0 = *(const float4*)wp;
    float4 w1 = *(const float4*)(wp + 4);      // cols kg8+4..7  (r3 bug was +8: wrong data + OOB->NaN)
    unsigned m8_0 = (unsigned)((mk0 >> (kk*32 + kg8)) & 0xffULL);
    unsigned m8_1 = (unsigned)((mk1 >> (kk*32 + kg8)) & 0xffULL);
    bf16x8 pa0 = mkpa(wh1_0, m8_0, w0, w1);
    bf16x8 pa1 = mkpa(wh1_1, m8_1, w0, w1);
    const int ko = kk*64 + kg*16;
    #pragma unroll
    for(int t=0;t<16;t++){
      int n = 16*t + (lane&15);
      bf16x8 bv = *(const bf16x8*)((const char*)&Vs[buf][0] + n*128 + (ko ^ ((n&7)<<4)));
      acc0[t] = __builtin_amdgcn_mfma_f32_16x16x32_bf16(pa0, bv, acc0[t], 0, 0, 0);
      acc1[t] = __builtin_amdgcn_mfma_f32_16x16x32_bf16(pa1, bv, acc1[t], 0, 0, 0);
    }
    accs0 = __builtin_amdgcn_mfma_f32_16x16x32_bf16(pa0, ones, accs0, 0, 0, 0);
    accs1 = __builtin_amdgcn_mfma_f32_16x16x32_bf16(pa1, ones, accs1, 0, 0, 0);
  };

  // prologue: stage V(0) + pack masks(0)
  stage(0, 0);
  adj_load(0);
  adj_pack(mk0, mk1);
  asm volatile("s_waitcnt vmcnt(0)" ::: "memory");
  __builtin_amdgcn_s_barrier();

  for(int it=0; it<16; it++){
    int buf = it & 1;
    if(it < 15){
      stage(it+1, buf^1);      // V prefetch -> LDS
      adj_load(it+1);          // adj prefetch -> regs (coalesced)
    }
    kstep(it, 0, buf);
    kstep(it, 1, buf);
    uint64_t mkn0 = 0, mkn1 = 0;
    if(it < 15) adj_pack(mkn0, mkn1);
    asm volatile("s_waitcnt vmcnt(0)" ::: "memory");
    __builtin_amdgcn_s_barrier();
    mk0 = mkn0; mk1 = mkn1;
  }

  const int orow0 = r0 + 16*w + 4*kg;
  const int orow1 = orow0 + 64;
  const int ocol  = lane & 15;
  if constexpr (PART){
    float* pv = pv_out + (size_t)chunk*GN*GOUT;
    float* sp = s_out  + (size_t)chunk*GN;
    #pragma unroll
    for(int t=0;t<16;t++){
      #pragma unroll
      for(int r=0;r<4;r++){
        pv[(size_t)(orow0 + r)*GOUT + ocol + 16*t] = acc0[t][r];
        pv[(size_t)(orow1 + r)*GOUT + ocol + 16*t] = acc1[t][r];
      }
    }
    if(ocol == 0){
      #pragma unroll
      for(int r=0;r<4;r++){ sp[orow0 + r] = accs0[r]; sp[orow1 + r] = accs1[r]; }
    }
  } else {
    #pragma unroll
    for(int t=0;t<16;t++){
      #pragma unroll
      for(int r=0;r<4;r++){
        atomicAdd(pv_out + (size_t)(orow0 + r)*GOUT + ocol + 16*t, acc0[t][r]);
        atomicAdd(pv_out + (size_t)(orow1 + r)*GOUT + ocol + 16*t, acc1[t][r]);
      }
    }
    if(ocol == 0){
      #pragma unroll
      for(int r=0;r<4;r++){ atomicAdd(s_out + orow0 + r, accs0[r]); atomicAdd(s_out + orow1 + r, accs1[r]); }
    }
  }
}

// ---------------- epilogues ----------------
static __device__ __forceinline__ float elu1(float x){
  return x > 0.f ? x : (exp2f(x*LOG2E) - 1.f);
}

// PART path: combine 8 partials + normalize + ELU
__global__ void k_reduce(const float* __restrict__ accP, const float* __restrict__ accSp,
                         float* __restrict__ out){
  size_t i = ((size_t)blockIdx.x*256 + threadIdx.x)*4;
  int row = (int)(i >> 8);
  float S = 0.f;
  #pragma unroll
  for(int c=0;c<8;c++) S += accSp[(size_t)c*GN + row];
  float4 s = {0.f,0.f,0.f,0.f};
  #pragma unroll
  for(int c=0;c<8;c++){
    float4 v = *(const float4*)(accP + (size_t)c*GN*GOUT + i);
    s.x += v.x; s.y += v.y; s.z += v.z; s.w += v.w;
  }
  float inv = 1.0f / S;
  float4 o;
  o.x = elu1(s.x*inv); o.y = elu1(s.y*inv); o.z = elu1(s.z*inv); o.w = elu1(s.w*inv);
  *(float4*)(out + i) = o;
}

// atomic path: normalize + ELU
__global__ void k_norm(const float* __restrict__ accPV, const float* __restrict__ accS,
                       float* __restrict__ out){
  size_t i = ((size_t)blockIdx.x*256 + threadIdx.x)*4;
  int row = (int)(i >> 8);
  float inv = 1.0f / accS[row];
  float4 v = *(const float4*)(accPV + i);
  float4 o;
  o.x = elu1(v.x*inv); o.y = elu1(v.y*inv); o.z = elu1(v.z*inv); o.w = elu1(v.w*inv);
  *(float4*)(out + i) = o;
}

// ---------------- launch ----------------
extern "C" void kernel_launch(void* const* d_in, const int* in_sizes, int n_in,
                              void* d_out, int out_size, void* d_ws, size_t ws_size,
                              hipStream_t stream){
  const float* h  = (const float*)d_in[0];
  const int*   adj= (const int*)  d_in[1];
  const float* W  = (const float*)d_in[2];
  const float* al = (const float*)d_in[3];
  const float* ar = (const float*)d_in[4];
  float* out = (float*)d_out;
  char* ws = (char*)d_ws;

  // partial-buffer layout: accP [0,67MB) aliases prep-only buffers (hb/WT/wal/war);
  // live-across-attn buffers (WhbT/Wh1/Wh2/accSp) sit above.
  const size_t SZ_ACCP = (size_t)8*GN*GOUT*4;        // 67,108,864
  const size_t NEED_A  = SZ_ACCP + 4194304 + 32768 + 32768 + 262144; // 71,630,848

  if(ws_size >= NEED_A){
    float*  accP  = (float*) (ws);
    __bf16* hb    = (__bf16*)(ws);                       // alias (prep-only)
    __bf16* WT    = (__bf16*)(ws + 8388608);             // alias (prep-only)
    float*  wal   = (float*) (ws + 8650752);             // alias (prep-only)
    float*  war   = (float*) (ws + 8652800);             // alias (prep-only)
    __bf16* WhbT  = (__bf16*)(ws + SZ_ACCP);
    float*  Wh1   = (float*) (ws + SZ_ACCP + 4194304);
    float*  Wh2   = (float*) (ws + SZ_ACCP + 4227072);
    float*  accSp = (float*) (ws + SZ_ACCP + 4259840);

    k_wa    <<<512, 64, 0, stream>>>(W, al, ar, wal, war);
    k_prep_h<<<2048, 256, 0, stream>>>(h, wal, war, hb, Wh1, Wh2);
    k_wt    <<<512, 256, 0, stream>>>(W, WT);
    k_gemmT <<<256, 256, 0, stream>>>(WT, hb, WhbT);
    k_attn<true><<<512, 256, 0, stream>>>(adj, WhbT, Wh1, Wh2, accP, accSp);
    k_reduce<<<2048, 256, 0, stream>>>(accP, accSp, out);
  } else {
    float*  accPV = (float*) (ws);                       //  8,388,608
    float*  accS  = (float*) (ws + 8388608);             //     32,768
    __bf16* hb    = (__bf16*)(ws + 8421376);             //  8,388,608
    __bf16* WT    = (__bf16*)(ws + 16809984);            //    262,144
    __bf16* WhbT  = (__bf16*)(ws + 17072128);            //  4,194,304
    float*  wal   = (float*) (ws + 21266432);
    float*  war   = (float*) (ws + 21268480);
    float*  Wh1   = (float*) (ws + 21270528);
    float*  Wh2   = (float*) (ws + 21303296);
    if(ws_size < 21336064) return;

    hipMemsetAsync(accPV, 0, 8388608 + 32768, stream);
    k_wa    <<<512, 64, 0, stream>>>(W, al, ar, wal, war);
    k_prep_h<<<2048, 256, 0, stream>>>(h, wal, war, hb, Wh1, Wh2);
    k_wt    <<<512, 256, 0, stream>>>(W, WT);
    k_gemmT <<<256, 256, 0, stream>>>(WT, hb, WhbT);
    k_attn<false><<<512, 256, 0, stream>>>(adj, WhbT, Wh1, Wh2, accPV, accS);
    k_norm  <<<2048, 256, 0, stream>>>(accPV, accS, out);
  }
}